// Round 3
// baseline (57.152 us; speedup 1.0000x reference)
//
#include <hip/hip_runtime.h>

// GazePreprocessor: out[b,t,0,h,w] = normalized separable-Gaussian splat of up
// to 5 weighted gaze points. Faithful reference math reduces to:
//   rows h in [60,120):  v[h][w] = sum_p wt_p * K[y_p - h + 60] * K[x_p - w + 60]
//   all other rows: exactly 0
//   out = v / (max(v) + 1e-8)   (per frame)
// One 256-thread block per frame; factors staged in LDS; write-BW bound.

namespace {
constexpr int IMG_H   = 180;
constexpr int IMG_W   = 320;
constexpr int KSIZE   = 121;
constexpr int PAD     = 60;
constexpr int MAXP    = 5;
constexpr int MIDROW0 = 60;              // first nonzero output row
constexpr int MIDROWS = 60;              // rows 60..119 nonzero
constexpr int W4      = IMG_W / 4;       // 80 float4 per row
constexpr int BLOCK   = 256;
}

typedef float vfloat4 __attribute__((ext_vector_type(4)));

__global__ __launch_bounds__(BLOCK) void gaze_blur_kernel(
    const float* __restrict__ coords,   // [N, MAXP, 2]  (x,y) in [0,1]
    const float* __restrict__ k1d,      // [121] gaussian, sums to 1
    float* __restrict__ out)            // [N, 180, 320]
{
    __shared__ float sK[KSIZE];
    __shared__ float sColW[MAXP][IMG_W];     // wt_p * K[x_p - w + PAD]
    __shared__ float sRowK[MAXP][MIDROWS];   // K[y_p - g], g = h - 60
    __shared__ int   sX[MAXP], sY[MAXP];
    __shared__ float sWt[MAXP];
    __shared__ float sWaveMax[BLOCK / 64];
    __shared__ float sInv;

    const int f   = blockIdx.x;
    const int tid = threadIdx.x;

    for (int i = tid; i < KSIZE; i += BLOCK) sK[i] = k1d[i];

    if (tid == 0) {
        const float* c = coords + (long)f * (MAXP * 2);
        int cum = 0;
        #pragma unroll
        for (int p = 0; p < MAXP; ++p) {
            float x = c[2 * p + 0];
            float y = c[2 * p + 1];
            bool valid = (x >= 0.0f) && (y >= 0.0f);
            float xf = fminf(fmaxf(x, 0.0f), 1.0f) * (float)(IMG_W - 1);
            float yf = fminf(fmaxf(y, 0.0f), 1.0f) * (float)(IMG_H - 1);
            int xi = (int)xf; xi = xi < 0 ? 0 : (xi > IMG_W - 1 ? IMG_W - 1 : xi);
            int yi = (int)yf; yi = yi < 0 ? 0 : (yi > IMG_H - 1 ? IMG_H - 1 : yi);
            cum += valid ? 1 : 0;
            int rk = cum - 1; if (rk < 0) rk = 0;       // clip(rank, 0)
            float w = 1.0f;
            for (int r = 0; r < rk; ++r) w *= 0.8f;     // COEFF^rank
            sX[p] = xi;
            sY[p] = yi;
            sWt[p] = valid ? w : 0.0f;
        }
    }
    __syncthreads();

    // Per-point column factors (weight folded in) and row factors.
    for (int i = tid; i < MAXP * IMG_W; i += BLOCK) {
        int p = i / IMG_W, w = i - p * IMG_W;
        int idx = sX[p] - w + PAD;                       // kw = x - w + 60
        sColW[p][w] = (idx >= 0 && idx < KSIZE) ? sK[idx] * sWt[p] : 0.0f;
    }
    for (int i = tid; i < MAXP * MIDROWS; i += BLOCK) {
        int p = i / MIDROWS, g = i - p * MIDROWS;
        int idx = sY[p] - g;                             // kh = y - (h-60) = y - g
        sRowK[p][g] = (idx >= 0 && idx < KSIZE) ? sK[idx] : 0.0f;
    }
    __syncthreads();

    // Pass 1: max over the 60 nonzero rows (values are all >= 0).
    float lmax = 0.0f;
    for (int j = tid; j < MIDROWS * W4; j += BLOCK) {
        int g  = j / W4;
        int wq = j - g * W4;
        float a = 0.f, b = 0.f, c2 = 0.f, d = 0.f;
        #pragma unroll
        for (int p = 0; p < MAXP; ++p) {
            float r = sRowK[p][g];
            vfloat4 cv = ((const vfloat4*)sColW[p])[wq];  // ds_read_b128
            a  = fmaf(r, cv.x, a);
            b  = fmaf(r, cv.y, b);
            c2 = fmaf(r, cv.z, c2);
            d  = fmaf(r, cv.w, d);
        }
        lmax = fmaxf(lmax, fmaxf(fmaxf(a, b), fmaxf(c2, d)));
    }
    #pragma unroll
    for (int off = 32; off >= 1; off >>= 1)
        lmax = fmaxf(lmax, __shfl_xor(lmax, off, 64));
    if ((tid & 63) == 0) sWaveMax[tid >> 6] = lmax;
    __syncthreads();
    if (tid == 0) {
        float m = sWaveMax[0];
        #pragma unroll
        for (int wv = 1; wv < BLOCK / 64; ++wv) m = fmaxf(m, sWaveMax[wv]);
        sInv = 1.0f / (m + 1e-8f);
    }
    __syncthreads();
    const float inv = sInv;

    // Pass 2: stream the full frame out (zeros outside middle rows).
    vfloat4* out4 = (vfloat4*)(out + (long)f * (IMG_H * IMG_W));
    for (int j = tid; j < (IMG_H * IMG_W) / 4; j += BLOCK) {
        int row = j / W4;
        vfloat4 v = (vfloat4)(0.0f);
        if (row >= MIDROW0 && row < MIDROW0 + MIDROWS) {
            int g  = row - MIDROW0;
            int wq = j - row * W4;
            float a = 0.f, b = 0.f, c2 = 0.f, d = 0.f;
            #pragma unroll
            for (int p = 0; p < MAXP; ++p) {
                float r = sRowK[p][g];
                vfloat4 cv = ((const vfloat4*)sColW[p])[wq];
                a  = fmaf(r, cv.x, a);
                b  = fmaf(r, cv.y, b);
                c2 = fmaf(r, cv.z, c2);
                d  = fmaf(r, cv.w, d);
            }
            v.x = a * inv; v.y = b * inv; v.z = c2 * inv; v.w = d * inv;
        }
        __builtin_nontemporal_store(v, out4 + j);
    }
}

extern "C" void kernel_launch(void* const* d_in, const int* in_sizes, int n_in,
                              void* d_out, int out_size, void* d_ws, size_t ws_size,
                              hipStream_t stream) {
    const float* coords = (const float*)d_in[0];   // [B,T,10] f32
    const float* k1d    = (const float*)d_in[1];   // [121] f32
    float* out          = (float*)d_out;           // [B,T,1,180,320] f32
    const int N = in_sizes[0] / (MAXP * 2);        // B*T = 1024 frames
    gaze_blur_kernel<<<N, BLOCK, 0, stream>>>(coords, k1d, out);
}

// Round 4
// 54.034 us; speedup vs baseline: 1.0577x; 1.0577x over previous
//
#include <hip/hip_runtime.h>

// GazePreprocessor. Reference math reduces to:
//   rows h in [60,120):  v[h][w] = sum_p wt_p * K[y_p-h+60] * K[x_p-w+60]
//   all other rows: exactly 0;  out = v / (max(v) + 1e-8) per frame.
// Round-4 structure: issue the 157 MB of zero-row stores FIRST (no data dep),
// hide the max-pass compute under them, keep mid-row values in registers,
// and use a vmcnt-free raw barrier for the max reduction so zero stores stay
// in flight. One 320-thread block per frame (80 float4 columns x 4 row-groups).

namespace {
constexpr int IMG_H   = 180;
constexpr int IMG_W   = 320;
constexpr int KSIZE   = 121;
constexpr int PAD     = 60;
constexpr int MAXP    = 5;
constexpr int MID0    = 60;            // first nonzero row
constexpr int MIDR    = 60;            // rows 60..119 nonzero
constexpr int W4      = IMG_W / 4;     // 80 float4 per row
constexpr int BLOCK   = 320;           // 80 quads x 4 row-groups = 5 waves
constexpr int NW      = BLOCK / 64;    // 5 waves
constexpr int GROUPS  = 4;
constexpr int ROWS_PT = MIDR / GROUPS; // 15 mid rows per thread
}

typedef float vfloat4 __attribute__((ext_vector_type(4)));

__global__ __launch_bounds__(BLOCK) void gaze_kernel(
    const float* __restrict__ coords,   // [N, MAXP, 2]
    const float* __restrict__ k1d,      // [121]
    float* __restrict__ out)            // [N, 180, 320]
{
    __shared__ float sK[KSIZE];
    __shared__ float sC[MAXP * 2];
    __shared__ float sColW[MAXP][IMG_W];   // wt_p * K[x_p - w + 60]
    __shared__ float sRowK[MAXP][MIDR];    // K[y_p - g]
    __shared__ float sWaveMax[NW];

    const int f   = blockIdx.x;
    const int tid = threadIdx.x;
    const int wq  = tid % W4;              // float4 column this thread owns
    const int grp = tid / W4;              // row-group 0..3

    // ---- phase 0: tiny global loads (only vmcnt-bearing ops in the kernel)
    if (tid < KSIZE) sK[tid] = k1d[tid];
    if (tid >= KSIZE && tid < KSIZE + MAXP * 2)
        sC[tid - KSIZE] = coords[(long)f * (MAXP * 2) + (tid - KSIZE)];
    __syncthreads();

    // ---- phase 1: point params replicated per-thread (registers, no serial tid0)
    int xi[MAXP], yi[MAXP];
    float wt[MAXP];
    {
        int cum = 0;
        #pragma unroll
        for (int p = 0; p < MAXP; ++p) {
            float x = sC[2 * p], y = sC[2 * p + 1];
            bool valid = (x >= 0.0f) && (y >= 0.0f);
            float xf = fminf(fmaxf(x, 0.0f), 1.0f) * (float)(IMG_W - 1);
            float yf = fminf(fmaxf(y, 0.0f), 1.0f) * (float)(IMG_H - 1);
            int xq = (int)xf; xq = xq < 0 ? 0 : (xq > IMG_W - 1 ? IMG_W - 1 : xq);
            int yq = (int)yf; yq = yq < 0 ? 0 : (yq > IMG_H - 1 ? IMG_H - 1 : yq);
            cum += valid ? 1 : 0;
            int rk = cum - 1; if (rk < 0) rk = 0;
            float w = 1.0f;
            for (int r = 0; r < rk; ++r) w *= 0.8f;     // COEFF^rank
            xi[p] = xq; yi[p] = yq; wt[p] = valid ? w : 0.0f;
        }
    }
    // factor tables: 320 threads exactly cover the 320 columns
    #pragma unroll
    for (int p = 0; p < MAXP; ++p) {
        int idx = xi[p] - tid + PAD;
        sColW[p][tid] = (idx >= 0 && idx < KSIZE) ? sK[idx] * wt[p] : 0.0f;
    }
    if (tid < MAXP * MIDR) {
        int p = tid / MIDR, g = tid - p * MIDR;
        int idx = yi[p] - g;
        sRowK[p][g] = (idx >= 0 && idx < KSIZE) ? sK[idx] : 0.0f;
    }
    __syncthreads();

    // ---- phase 2: zero-row stores (2/3 of all bytes, zero data deps) — issue
    // immediately so HBM write BW is saturated while we compute the max.
    vfloat4* out4 = (vfloat4*)(out + (long)f * (IMG_H * IMG_W));
    const vfloat4 z = (vfloat4)(0.0f);
    #pragma unroll
    for (int i = 0; i < ROWS_PT; ++i) {
        __builtin_nontemporal_store(z, out4 + (i * 4 + grp) * W4 + wq);
        __builtin_nontemporal_store(z, out4 + ((120 + i * 4 + grp) * W4 + wq));
    }

    // ---- phase 3: mid-row values into registers (hoisted column factors)
    vfloat4 cv0 = ((const vfloat4*)sColW[0])[wq];
    vfloat4 cv1 = ((const vfloat4*)sColW[1])[wq];
    vfloat4 cv2 = ((const vfloat4*)sColW[2])[wq];
    vfloat4 cv3 = ((const vfloat4*)sColW[3])[wq];
    vfloat4 cv4 = ((const vfloat4*)sColW[4])[wq];
    vfloat4 vals[ROWS_PT];
    float lmax = 0.0f;
    #pragma unroll
    for (int i = 0; i < ROWS_PT; ++i) {
        int g = i * 4 + grp;
        vfloat4 a;
        a = sRowK[0][g] * cv0;
        a += sRowK[1][g] * cv1;
        a += sRowK[2][g] * cv2;
        a += sRowK[3][g] * cv3;
        a += sRowK[4][g] * cv4;
        vals[i] = a;
        lmax = fmaxf(lmax, fmaxf(fmaxf(a.x, a.y), fmaxf(a.z, a.w)));
    }

    // ---- phase 4: block max WITHOUT draining the zero stores:
    // raw s_barrier with lgkmcnt(0) only (no vmcnt(0)).
    #pragma unroll
    for (int off = 32; off >= 1; off >>= 1)
        lmax = fmaxf(lmax, __shfl_xor(lmax, off, 64));
    if ((tid & 63) == 0) sWaveMax[tid >> 6] = lmax;
    asm volatile("s_waitcnt lgkmcnt(0)" ::: "memory");
    __builtin_amdgcn_s_barrier();
    __builtin_amdgcn_sched_barrier(0);
    float m = sWaveMax[0];
    #pragma unroll
    for (int wv = 1; wv < NW; ++wv) m = fmaxf(m, sWaveMax[wv]);
    const float inv = 1.0f / (m + 1e-8f);

    // ---- phase 5: scale registers and stream mid rows (no recompute)
    #pragma unroll
    for (int i = 0; i < ROWS_PT; ++i) {
        vfloat4 v = vals[i] * inv;
        __builtin_nontemporal_store(v, out4 + ((MID0 + i * 4 + grp) * W4 + wq));
    }
}

extern "C" void kernel_launch(void* const* d_in, const int* in_sizes, int n_in,
                              void* d_out, int out_size, void* d_ws, size_t ws_size,
                              hipStream_t stream) {
    const float* coords = (const float*)d_in[0];   // [B,T,10] f32
    const float* k1d    = (const float*)d_in[1];   // [121] f32
    float* out          = (float*)d_out;           // [B,T,1,180,320] f32
    const int N = in_sizes[0] / (MAXP * 2);        // B*T = 1024 frames
    gaze_kernel<<<N, BLOCK, 0, stream>>>(coords, k1d, out);
}

// Round 5
// 40.633 us; speedup vs baseline: 1.4065x; 1.3298x over previous
//
#include <hip/hip_runtime.h>

// GazePreprocessor. Reference math reduces to:
//   rows h in [60,120):  v[h][w] = sum_p wt_p * K[y_p-h+60] * K[x_p-w+60]
//   all other rows: exactly 0;  out = v / (max(v) + 1e-8) per frame.
// Round-5 structure: role-split grid. Blocks [0,N) compute the 60 mid rows of
// frame b (values held in registers, one barrier-reduce for the max). Blocks
// [N,2N) are pure fill blocks (no LDS use, no barrier, no prologue) that
// stream frame (b-N)'s 120 zero rows exactly like rocclr fillBuffer, which
// measures 6.7-6.9 TB/s on this pod. Plain (non-NT) dwordx4 stores everywhere.

namespace {
constexpr int IMG_H   = 180;
constexpr int IMG_W   = 320;
constexpr int KSIZE   = 121;
constexpr int PAD     = 60;
constexpr int MAXP    = 5;
constexpr int MID0    = 60;            // first nonzero row
constexpr int MIDR    = 60;            // rows 60..119 nonzero
constexpr int W4      = IMG_W / 4;     // 80 float4 per row
constexpr int FRAMEQ  = IMG_H * W4;    // 14400 float4 per frame
constexpr int BLOCK   = 320;           // 80 quads x 4 row-groups = 5 waves
constexpr int NW      = BLOCK / 64;    // 5 waves
constexpr int GROUPS  = 4;
constexpr int ROWS_PT = MIDR / GROUPS; // 15 mid rows per thread
}

typedef float vfloat4 __attribute__((ext_vector_type(4)));

__global__ __launch_bounds__(BLOCK) void gaze_kernel(
    const float* __restrict__ coords,   // [N, MAXP, 2]
    const float* __restrict__ k1d,      // [121]
    float* __restrict__ out,            // [N, 180, 320]
    int nframes)
{
    const int bid = blockIdx.x;
    const int tid = threadIdx.x;

    if (bid >= nframes) {
        // ---------------- fill block: 120 zero rows of one frame ----------
        const int f = bid - nframes;
        vfloat4* o = (vfloat4*)out + (size_t)f * FRAMEQ;
        const vfloat4 z = (vfloat4)(0.0f);
        #pragma unroll
        for (int i = 0; i < 15; ++i) {            // 4800 quads per band
            o[tid + i * BLOCK] = z;               // rows 0..59
            o[9600 + tid + i * BLOCK] = z;        // rows 120..179
        }
        return;
    }

    // ---------------- compute block: 60 mid rows of one frame -------------
    __shared__ float sK[KSIZE];
    __shared__ float sC[MAXP * 2];
    __shared__ float sColW[MAXP][IMG_W];   // wt_p * K[x_p - w + 60]
    __shared__ float sRowK[MAXP][MIDR];    // K[y_p - g]
    __shared__ float sWaveMax[NW];

    const int f   = bid;
    const int wq  = tid % W4;              // float4 column this thread owns
    const int grp = tid / W4;              // row-group 0..3

    if (tid < KSIZE) sK[tid] = k1d[tid];
    if (tid >= KSIZE && tid < KSIZE + MAXP * 2)
        sC[tid - KSIZE] = coords[(long)f * (MAXP * 2) + (tid - KSIZE)];
    __syncthreads();

    int xi[MAXP], yi[MAXP];
    float wt[MAXP];
    {
        int cum = 0;
        #pragma unroll
        for (int p = 0; p < MAXP; ++p) {
            float x = sC[2 * p], y = sC[2 * p + 1];
            bool valid = (x >= 0.0f) && (y >= 0.0f);
            float xf = fminf(fmaxf(x, 0.0f), 1.0f) * (float)(IMG_W - 1);
            float yf = fminf(fmaxf(y, 0.0f), 1.0f) * (float)(IMG_H - 1);
            int xq = (int)xf; xq = xq < 0 ? 0 : (xq > IMG_W - 1 ? IMG_W - 1 : xq);
            int yq = (int)yf; yq = yq < 0 ? 0 : (yq > IMG_H - 1 ? IMG_H - 1 : yq);
            cum += valid ? 1 : 0;
            int rk = cum - 1; if (rk < 0) rk = 0;
            float w = 1.0f;
            for (int r = 0; r < rk; ++r) w *= 0.8f;     // COEFF^rank
            xi[p] = xq; yi[p] = yq; wt[p] = valid ? w : 0.0f;
        }
    }
    #pragma unroll
    for (int p = 0; p < MAXP; ++p) {
        int idx = xi[p] - tid + PAD;
        sColW[p][tid] = (idx >= 0 && idx < KSIZE) ? sK[idx] * wt[p] : 0.0f;
    }
    if (tid < MAXP * MIDR) {
        int p = tid / MIDR, g = tid - p * MIDR;
        int idx = yi[p] - g;
        sRowK[p][g] = (idx >= 0 && idx < KSIZE) ? sK[idx] : 0.0f;
    }
    __syncthreads();

    // mid-row values into registers (hoisted column factors)
    vfloat4 cv0 = ((const vfloat4*)sColW[0])[wq];
    vfloat4 cv1 = ((const vfloat4*)sColW[1])[wq];
    vfloat4 cv2 = ((const vfloat4*)sColW[2])[wq];
    vfloat4 cv3 = ((const vfloat4*)sColW[3])[wq];
    vfloat4 cv4 = ((const vfloat4*)sColW[4])[wq];
    vfloat4 vals[ROWS_PT];
    float lmax = 0.0f;
    #pragma unroll
    for (int i = 0; i < ROWS_PT; ++i) {
        int g = i * 4 + grp;
        vfloat4 a;
        a  = sRowK[0][g] * cv0;
        a += sRowK[1][g] * cv1;
        a += sRowK[2][g] * cv2;
        a += sRowK[3][g] * cv3;
        a += sRowK[4][g] * cv4;
        vals[i] = a;
        lmax = fmaxf(lmax, fmaxf(fmaxf(a.x, a.y), fmaxf(a.z, a.w)));
    }

    // block max reduce
    #pragma unroll
    for (int off = 32; off >= 1; off >>= 1)
        lmax = fmaxf(lmax, __shfl_xor(lmax, off, 64));
    if ((tid & 63) == 0) sWaveMax[tid >> 6] = lmax;
    __syncthreads();
    float m = sWaveMax[0];
    #pragma unroll
    for (int wv = 1; wv < NW; ++wv) m = fmaxf(m, sWaveMax[wv]);
    const float inv = 1.0f / (m + 1e-8f);

    // scale registers and stream the 60 mid rows
    vfloat4* out4 = (vfloat4*)out + (size_t)f * FRAMEQ;
    #pragma unroll
    for (int i = 0; i < ROWS_PT; ++i) {
        vfloat4 v = vals[i] * inv;
        out4[(MID0 + i * 4 + grp) * W4 + wq] = v;
    }
}

extern "C" void kernel_launch(void* const* d_in, const int* in_sizes, int n_in,
                              void* d_out, int out_size, void* d_ws, size_t ws_size,
                              hipStream_t stream) {
    const float* coords = (const float*)d_in[0];   // [B,T,10] f32
    const float* k1d    = (const float*)d_in[1];   // [121] f32
    float* out          = (float*)d_out;           // [B,T,1,180,320] f32
    const int N = in_sizes[0] / (MAXP * 2);        // B*T = 1024 frames
    gaze_kernel<<<2 * N, BLOCK, 0, stream>>>(coords, k1d, out, N);
}

// Round 6
// 35.491 us; speedup vs baseline: 1.6103x; 1.1449x over previous
//
#include <hip/hip_runtime.h>

// GazePreprocessor. Reference math reduces to:
//   rows h in [60,120):  v[h][w] = sum_p wt_p * K[y_p-h+60] * K[x_p-w+60]
//   all other rows: exactly 0;  out = v / (max(v) + 1e-8) per frame.
// Round-6: role-split grid + leading zero burst in compute blocks.
//   blocks [0,N):  frame f — store rows 0..59 (zeros) FIRST (hides the
//                  prologue under stores), then factor tables, max-reduce
//                  (raw lgkm-only barriers: never drain vmcnt), then rows
//                  60..119 recomputed+scaled from registers/LDS.
//   blocks [N,2N): pure fill of rows 120..179 (no LDS, no barrier).
// Plain dwordx4 stores throughout (matches the 6.9 TB/s rocclr fill).

namespace {
constexpr int IMG_H   = 180;
constexpr int IMG_W   = 320;
constexpr int KSIZE   = 121;
constexpr int PAD     = 60;
constexpr int MAXP    = 5;
constexpr int MID0    = 60;
constexpr int MIDR    = 60;
constexpr int W4      = IMG_W / 4;      // 80 float4 per row
constexpr int FRAMEQ  = IMG_H * W4;     // 14400 float4 per frame
constexpr int BLOCK   = 320;            // 80 quads x 4 row-groups = 5 waves
constexpr int NW      = BLOCK / 64;
constexpr int ROWS_PT = 15;             // rows per thread within a 60-row band
}

typedef float vfloat4 __attribute__((ext_vector_type(4)));

__device__ __forceinline__ void raw_barrier_lgkm() {
    // barrier that does NOT drain vmcnt (keeps zero stores in flight)
    asm volatile("s_waitcnt lgkmcnt(0)" ::: "memory");
    __builtin_amdgcn_s_barrier();
    __builtin_amdgcn_sched_barrier(0);   // rule #18: block hoisting past the wait
}

__global__ __launch_bounds__(BLOCK) void gaze_kernel(
    const float* __restrict__ coords,   // [N, MAXP, 2]
    const float* __restrict__ k1d,      // [121]
    float* __restrict__ out,            // [N, 180, 320]
    int nframes)
{
    const int bid = blockIdx.x;
    const int tid = threadIdx.x;

    if (bid >= nframes) {
        // ---------- fill block: rows 120..179 of one frame (75 KB) --------
        vfloat4* o = (vfloat4*)out + (size_t)(bid - nframes) * FRAMEQ + 9600;
        const vfloat4 z = (vfloat4)(0.0f);
        #pragma unroll
        for (int i = 0; i < ROWS_PT; ++i)
            o[tid + i * BLOCK] = z;
        return;
    }

    // ---------- compute block: rows 0..59 (zeros) + rows 60..119 ----------
    __shared__ float sK[KSIZE];
    __shared__ float sC[MAXP * 2];
    __shared__ float sColW[MAXP][IMG_W];   // wt_p * K[x_p - w + 60]
    __shared__ float sRowK[MAXP][MIDR];    // K[y_p - g]
    __shared__ float sWaveMax[NW];

    const int f   = bid;
    const int wq  = tid % W4;
    const int grp = tid / W4;

    // 1) issue the tiny global loads FIRST (oldest in vmcnt order)
    float kreg = 0.0f, creg = 0.0f;
    if (tid < KSIZE) kreg = k1d[tid];
    if (tid >= 128 && tid < 128 + MAXP * 2)
        creg = coords[(long)f * (MAXP * 2) + (tid - 128)];

    // 2) leading zero burst: rows 0..59 — saturates the store pipe while the
    //    prologue's load latency and LDS setup happen underneath it.
    vfloat4* out4 = (vfloat4*)out + (size_t)f * FRAMEQ;
    const vfloat4 z = (vfloat4)(0.0f);
    #pragma unroll
    for (int i = 0; i < ROWS_PT; ++i)
        out4[(i * 4 + grp) * W4 + wq] = z;
    __builtin_amdgcn_sched_barrier(0);   // pin the burst before the LDS phase

    // 3) publish to LDS
    if (tid < KSIZE) sK[tid] = kreg;
    if (tid >= 128 && tid < 128 + MAXP * 2) sC[tid - 128] = creg;
    raw_barrier_lgkm();

    // 4) per-thread point params
    int xi[MAXP], yi[MAXP];
    float wt[MAXP];
    {
        int cum = 0;
        #pragma unroll
        for (int p = 0; p < MAXP; ++p) {
            float x = sC[2 * p], y = sC[2 * p + 1];
            bool valid = (x >= 0.0f) && (y >= 0.0f);
            float xf = fminf(fmaxf(x, 0.0f), 1.0f) * (float)(IMG_W - 1);
            float yf = fminf(fmaxf(y, 0.0f), 1.0f) * (float)(IMG_H - 1);
            int xq = (int)xf; xq = xq < 0 ? 0 : (xq > IMG_W - 1 ? IMG_W - 1 : xq);
            int yq = (int)yf; yq = yq < 0 ? 0 : (yq > IMG_H - 1 ? IMG_H - 1 : yq);
            cum += valid ? 1 : 0;
            int rk = cum - 1; if (rk < 0) rk = 0;
            float w = 1.0f;
            for (int r = 0; r < rk; ++r) w *= 0.8f;     // COEFF^rank
            xi[p] = xq; yi[p] = yq; wt[p] = valid ? w : 0.0f;
        }
    }
    // factor tables (320 threads cover the 320 columns exactly)
    #pragma unroll
    for (int p = 0; p < MAXP; ++p) {
        int idx = xi[p] - tid + PAD;
        sColW[p][tid] = (idx >= 0 && idx < KSIZE) ? sK[idx] * wt[p] : 0.0f;
    }
    if (tid < MAXP * MIDR) {
        int p = tid / MIDR, g = tid - p * MIDR;
        int idx = yi[p] - g;
        sRowK[p][g] = (idx >= 0 && idx < KSIZE) ? sK[idx] : 0.0f;
    }
    raw_barrier_lgkm();

    // 5) max pass (values recomputed later — keeps VGPR low for occupancy)
    vfloat4 cv0 = ((const vfloat4*)sColW[0])[wq];
    vfloat4 cv1 = ((const vfloat4*)sColW[1])[wq];
    vfloat4 cv2 = ((const vfloat4*)sColW[2])[wq];
    vfloat4 cv3 = ((const vfloat4*)sColW[3])[wq];
    vfloat4 cv4 = ((const vfloat4*)sColW[4])[wq];
    float lmax = 0.0f;
    #pragma unroll
    for (int i = 0; i < ROWS_PT; ++i) {
        int g = i * 4 + grp;
        vfloat4 a;
        a  = sRowK[0][g] * cv0;
        a += sRowK[1][g] * cv1;
        a += sRowK[2][g] * cv2;
        a += sRowK[3][g] * cv3;
        a += sRowK[4][g] * cv4;
        lmax = fmaxf(lmax, fmaxf(fmaxf(a.x, a.y), fmaxf(a.z, a.w)));
    }
    #pragma unroll
    for (int off = 32; off >= 1; off >>= 1)
        lmax = fmaxf(lmax, __shfl_xor(lmax, off, 64));
    if ((tid & 63) == 0) sWaveMax[tid >> 6] = lmax;
    raw_barrier_lgkm();
    float m = sWaveMax[0];
    #pragma unroll
    for (int wv = 1; wv < NW; ++wv) m = fmaxf(m, sWaveMax[wv]);
    const float inv = 1.0f / (m + 1e-8f);

    // 6) recompute, scale, stream rows 60..119
    #pragma unroll
    for (int i = 0; i < ROWS_PT; ++i) {
        int g = i * 4 + grp;
        vfloat4 a;
        a  = sRowK[0][g] * cv0;
        a += sRowK[1][g] * cv1;
        a += sRowK[2][g] * cv2;
        a += sRowK[3][g] * cv3;
        a += sRowK[4][g] * cv4;
        out4[(MID0 + g) * W4 + wq] = a * inv;
    }
}

extern "C" void kernel_launch(void* const* d_in, const int* in_sizes, int n_in,
                              void* d_out, int out_size, void* d_ws, size_t ws_size,
                              hipStream_t stream) {
    const float* coords = (const float*)d_in[0];   // [B,T,10] f32
    const float* k1d    = (const float*)d_in[1];   // [121] f32
    float* out          = (float*)d_out;           // [B,T,1,180,320] f32
    const int N = in_sizes[0] / (MAXP * 2);        // B*T = 1024 frames
    gaze_kernel<<<2 * N, BLOCK, 0, stream>>>(coords, k1d, out, N);
}